// Round 3
// baseline (508.035 us; speedup 1.0000x reference)
//
#include <hip/hip_runtime.h>

#define NN 50000
#define NE 600000
#define NB 4096
#define DD 128
#define EPSV 1e-5f
#define NBKT 196     // ceil(50000/256) buckets of 256 node ids (per side)
#define NCHUNK 256   // edge chunks per side
#define CHSZ ((NE + NCHUNK - 1) / NCHUNK)   // 2344

typedef __bf16 bf16x8 __attribute__((ext_vector_type(8)));
typedef float f32x4 __attribute__((ext_vector_type(4)));

__device__ inline unsigned short f2bf(float f) {
    unsigned u = __float_as_uint(f);
    u = (u + 0x7FFFu + ((u >> 16) & 1u)) >> 16;
    return (unsigned short)u;
}
__device__ inline float bf2f(unsigned short h) {
    return __uint_as_float(((unsigned)h) << 16);
}

// ---------------- input conversion: fp32 -> hi/lo bf16 planes (both sides) ----------------
__global__ void k_cvt(const float* __restrict__ x1, const float* __restrict__ x2,
                      unsigned short* __restrict__ xh, unsigned short* __restrict__ xl) {
    int i = blockIdx.x * 256 + threadIdx.x;          // over 2*NN*32 float4 groups
    if (i >= 2 * NN * 32) return;
    const float* x = (i < NN * 32) ? x1 : x2;
    int j = (i < NN * 32) ? i : i - NN * 32;
    float4 v = ((const float4*)x)[j];
    ushort4 h, l;
    h.x = f2bf(v.x); l.x = f2bf(v.x - bf2f(h.x));
    h.y = f2bf(v.y); l.y = f2bf(v.y - bf2f(h.y));
    h.z = f2bf(v.z); l.z = f2bf(v.z - bf2f(h.z));
    h.w = f2bf(v.w); l.w = f2bf(v.w - bf2f(h.w));
    ((ushort4*)xh)[i] = h;
    ((ushort4*)xl)[i] = l;
}

// W1 packed hi|lo uint for the MLP head: W1t[n][k], k in [0,384)
__global__ void k_wcvt(const float* __restrict__ W1, unsigned* __restrict__ wtp) {
    int t = blockIdx.x * 256 + threadIdx.x;
    if (t >= 128 * 384) return;
    int n = t / 384;
    int k = t - n * 384;
    float w = W1[k * 128 + n];
    unsigned short h = f2bf(w);
    unsigned short l = f2bf(w - bf2f(h));
    wtp[t] = ((unsigned)h << 16) | (unsigned)l;
}

// SAGE weights -> MFMA-fragment-linear bf16 hi/lo planes.
// Per layer l: 64 fragments f = (ntile*8 + kc), each 1024 ushorts:
//   [0..511]   hi plane: lane = kq*16+fm holds W[n=ntile*16+fm][k=kc*32+kq*8+j], j=0..7
//   [512..1023] lo plane, same order
// k<128 -> Wl[l][k][n] (applied to agg), k>=128 -> Wr[l][k-128][n] (applied to x)
__global__ void k_wfrag(const float* __restrict__ Wl, const float* __restrict__ Wr,
                        unsigned short* __restrict__ wf) {
    int t = blockIdx.x * 256 + threadIdx.x;   // over 3*128*256 elems
    if (t >= 3 * 128 * 256) return;
    int k = t & 255;
    int n = (t >> 8) & 127;
    int l = t >> 15;
    float w = (k < 128) ? Wl[l * 16384 + k * 128 + n] : Wr[l * 16384 + (k - 128) * 128 + n];
    unsigned short h = f2bf(w);
    unsigned short lo = f2bf(w - bf2f(h));
    int ntile = n >> 4, fm = n & 15, kc = k >> 5, kq = (k & 31) >> 3, j = k & 7;
    size_t pos = (size_t)l * 65536 + (size_t)(ntile * 8 + kc) * 1024 + (size_t)(kq * 16 + fm) * 8 + j;
    wf[pos] = h;
    wf[pos + 512] = lo;
}

// ---------------- CSR build: atomic-free two-level counting sort (LDS atomics only) ----------------
__global__ void k_hist(const int* __restrict__ d0, const int* __restrict__ d1,
                       int* __restrict__ bcnt) {
    int side = (blockIdx.x >= NCHUNK) ? 1 : 0;
    int c = blockIdx.x - side * NCHUNK;
    const int* dst = side ? d1 : d0;
    int tid = threadIdx.x;
    __shared__ int h[NBKT];
    for (int i = tid; i < NBKT; i += 256) h[i] = 0;
    __syncthreads();
    int e0 = c * CHSZ, e1 = min(e0 + CHSZ, NE);
    for (int e = e0 + tid; e < e1; e += 256) atomicAdd(&h[dst[e] >> 8], 1);
    __syncthreads();
    int* bc = bcnt + ((size_t)side * NCHUNK + c) * NBKT;
    for (int i = tid; i < NBKT; i += 256) bc[i] = h[i];
}

__global__ void k_s1(int* __restrict__ bcnt, int* __restrict__ btot) {
    int side = (blockIdx.x >= NBKT) ? 1 : 0;
    int b = blockIdx.x - side * NBKT;
    int tid = threadIdx.x;            // tid == chunk
    int idx = ((size_t)side * NCHUNK + tid) * NBKT + b;
    int v = bcnt[idx];
    int lane = tid & 63, wv = tid >> 6;
    int x = v;
#pragma unroll
    for (int off = 1; off < 64; off <<= 1) {
        int y = __shfl_up(x, off, 64);
        if (lane >= off) x += y;
    }
    __shared__ int ws4[4];
    if (lane == 63) ws4[wv] = x;
    __syncthreads();
    int add = 0;
#pragma unroll
    for (int w = 0; w < 4; w++)
        if (w < wv) add += ws4[w];
    int incl = x + add;
    bcnt[idx] = incl - v;
    if (tid == 255) btot[side * NBKT + b] = incl;
}

__global__ void k_s2(const int* __restrict__ btot, int* __restrict__ bbase,
                     int* __restrict__ ptrC) {
    int side = blockIdx.x;
    int tid = threadIdx.x;
    int v = (tid < NBKT) ? btot[side * NBKT + tid] : 0;
    int lane = tid & 63, wv = tid >> 6;
    int x = v;
#pragma unroll
    for (int off = 1; off < 64; off <<= 1) {
        int y = __shfl_up(x, off, 64);
        if (lane >= off) x += y;
    }
    __shared__ int ws4[4];
    if (lane == 63) ws4[wv] = x;
    __syncthreads();
    int add = 0;
#pragma unroll
    for (int w = 0; w < 4; w++)
        if (w < wv) add += ws4[w];
    int incl = x + add;
    if (tid < NBKT) bbase[side * NBKT + tid] = incl - v;
    if (tid == 0 && side == 1) ptrC[2 * NN] = 2 * NE;
}

// partition: part[side*NE + pos] = (src_global << 8) | (dst & 255)
__global__ void k_part(const int* __restrict__ s0, const int* __restrict__ d0,
                       const int* __restrict__ s1, const int* __restrict__ d1,
                       const int* __restrict__ bcnt, const int* __restrict__ bbase,
                       int* __restrict__ part) {
    int side = (blockIdx.x >= NCHUNK) ? 1 : 0;
    int c = blockIdx.x - side * NCHUNK;
    const int* src = side ? s1 : s0;
    const int* dst = side ? d1 : d0;
    int tid = threadIdx.x;
    __shared__ int off[NBKT];
    const int* bc = bcnt + ((size_t)side * NCHUNK + c) * NBKT;
    for (int i = tid; i < NBKT; i += 256) off[i] = bbase[side * NBKT + i] + bc[i];
    __syncthreads();
    int e0 = c * CHSZ, e1 = min(e0 + CHSZ, NE);
    int* P = part + (size_t)side * NE;
    int soff = side * NN;
    for (int e = e0 + tid; e < e1; e += 256) {
        int d = dst[e];
        int pos = atomicAdd(&off[d >> 8], 1);
        P[pos] = ((src[e] + soff) << 8) | (d & 255);
    }
}

// per bucket: count, scan -> ptrC/invd (combined), place src into combined CSR
__global__ void k_csr(const int* __restrict__ part, const int* __restrict__ bbase,
                      int* __restrict__ ptrC, float* __restrict__ invdC,
                      int* __restrict__ csrC) {
    int side = (blockIdx.x >= NBKT) ? 1 : 0;
    int b = blockIdx.x - side * NBKT;
    int tid = threadIdx.x;
    const int* P = part + (size_t)side * NE;
    int base = bbase[side * NBKT + b];
    int endp = (b == NBKT - 1) ? NE : bbase[side * NBKT + b + 1];
    __shared__ int cnt[256];
    cnt[tid] = 0;
    __syncthreads();
    for (int e = base + tid; e < endp; e += 256) atomicAdd(&cnt[P[e] & 255], 1);
    __syncthreads();
    int v = cnt[tid];
    int lane = tid & 63, wv = tid >> 6;
    int x = v;
#pragma unroll
    for (int off = 1; off < 64; off <<= 1) {
        int y = __shfl_up(x, off, 64);
        if (lane >= off) x += y;
    }
    __shared__ int ws4[4];
    if (lane == 63) ws4[wv] = x;
    __syncthreads();
    int add = 0;
#pragma unroll
    for (int w = 0; w < 4; w++)
        if (w < wv) add += ws4[w];
    int excl = x + add - v;
    int node = (b << 8) + tid;
    if (node < NN) {
        ptrC[side * NN + node] = side * NE + base + excl;
        invdC[side * NN + node] = 1.0f / (float)(v > 1 ? v : 1);
    }
    __syncthreads();
    cnt[tid] = excl;
    __syncthreads();
    for (int e = base + tid; e < endp; e += 256) {
        int p = P[e];
        int pos = atomicAdd(&cnt[p & 255], 1);
        csrC[(size_t)side * NE + base + pos] = p >> 8;
    }
}

// ---------------- neighbor mean-aggregation (hi plane in, hi plane out; both sides) ----------------
// One wave per node; coalesced csr index load + __shfl distribution; 16 lanes/row x uint4.
__global__ void k_gather(const unsigned short* __restrict__ xh, const int* __restrict__ ptr,
                         const int* __restrict__ csr, const float* __restrict__ invd,
                         unsigned short* __restrict__ aggH) {
    int wid = threadIdx.x >> 6;
    int lane = threadIdx.x & 63;
    int q = lane >> 4;        // edge slot within group of 4
    int c = lane & 15;        // column chunk: elems [c*8, c*8+8)
    int n = blockIdx.x * 4 + wid;
    if (n >= 2 * NN) return;
    int beg = ptr[n], end = ptr[n + 1];
    float id = invd[n];
    float a[8];
#pragma unroll
    for (int k = 0; k < 8; k++) a[k] = 0.f;

    for (int base = beg; base < end; base += 64) {
        int cnt = min(end - base, 64);
        int idxv = csr[base + min(lane, cnt - 1)];
        for (int e0 = 0; e0 < cnt; e0 += 8) {
            int eA = e0 + q;
            int eB = e0 + 4 + q;
            int iA = __shfl(idxv, eA, 64);
            int iB = __shfl(idxv, eB, 64);
            float wA = (eA < cnt) ? 1.f : 0.f;
            float wB = (eB < cnt) ? 1.f : 0.f;
            uint4 vA = *(const uint4*)(xh + (((unsigned)iA << 7) + (c << 3)));
            uint4 vB = *(const uint4*)(xh + (((unsigned)iB << 7) + (c << 3)));
            a[0] += wA * __uint_as_float(vA.x << 16);
            a[1] += wA * __uint_as_float(vA.x & 0xffff0000u);
            a[2] += wA * __uint_as_float(vA.y << 16);
            a[3] += wA * __uint_as_float(vA.y & 0xffff0000u);
            a[4] += wA * __uint_as_float(vA.z << 16);
            a[5] += wA * __uint_as_float(vA.z & 0xffff0000u);
            a[6] += wA * __uint_as_float(vA.w << 16);
            a[7] += wA * __uint_as_float(vA.w & 0xffff0000u);
            a[0] += wB * __uint_as_float(vB.x << 16);
            a[1] += wB * __uint_as_float(vB.x & 0xffff0000u);
            a[2] += wB * __uint_as_float(vB.y << 16);
            a[3] += wB * __uint_as_float(vB.y & 0xffff0000u);
            a[4] += wB * __uint_as_float(vB.z << 16);
            a[5] += wB * __uint_as_float(vB.z & 0xffff0000u);
            a[6] += wB * __uint_as_float(vB.w << 16);
            a[7] += wB * __uint_as_float(vB.w & 0xffff0000u);
        }
    }
#pragma unroll
    for (int k = 0; k < 8; k++) {
        a[k] += __shfl_xor(a[k], 16, 64);
        a[k] += __shfl_xor(a[k], 32, 64);
    }
    if (q == 0) {
        unsigned short h0 = f2bf(a[0] * id), h1 = f2bf(a[1] * id);
        unsigned short h2 = f2bf(a[2] * id), h3 = f2bf(a[3] * id);
        unsigned short h4 = f2bf(a[4] * id), h5 = f2bf(a[5] * id);
        unsigned short h6 = f2bf(a[6] * id), h7 = f2bf(a[7] * id);
        uint4 o;
        o.x = (unsigned)h0 | ((unsigned)h1 << 16);
        o.y = (unsigned)h2 | ((unsigned)h3 << 16);
        o.z = (unsigned)h4 | ((unsigned)h5 << 16);
        o.w = (unsigned)h6 | ((unsigned)h7 << 16);
        *(uint4*)(aggH + (size_t)n * DD + c * 8) = o;
    }
}

// ---------------- fused SAGE layer GEMM: W-in-LDS (staged once), barrier-free main loop ----------
// Block = 4 waves; block tile = 128 rows x 32 cols (col-group g = blockIdx&3). W fragments for
// the 32 cols (hi+lo, fragment-linear) = 32 KB staged into LDS once, ONE __syncthreads, then a
// pure {A global loads + W LDS reads + MFMA} loop with no further barriers and conflict-free
// lane*16B LDS reads. 5 blocks/CU (LDS 5x32=160 KB) = 20 waves/CU hides the streaming A loads.
// 100000 % 32 == 0 -> wave-granular OOB guard only.
__launch_bounds__(256, 5)
__global__ void k_gemm3(const unsigned short* __restrict__ AH,
                        const unsigned short* __restrict__ XH, const unsigned short* __restrict__ XL,
                        const unsigned short* __restrict__ wf,
                        const float* __restrict__ bl, const float* __restrict__ g,
                        const float* __restrict__ be, const float* __restrict__ mn,
                        const float* __restrict__ vr,
                        unsigned short* __restrict__ OH, unsigned short* __restrict__ OL,
                        float* __restrict__ Of, int f32out) {
    __shared__ __align__(16) unsigned short sW[16384];   // 32 KB: 16 fragments x 1024 shorts
    int tid = threadIdx.x;
    int lane = tid & 63, w = tid >> 6;
    int fm = lane & 15, kq = lane >> 4;
    int gx = blockIdx.x;
    int grp = gx & 3;
    int m0 = (gx >> 2) * 128;

    {   // one-time W stage: 2048 uint4, fully coalesced, conflict-free
        const uint4* src = (const uint4*)wf + (size_t)grp * 2048;
        uint4* dst = (uint4*)sW;
#pragma unroll
        for (int i = 0; i < 8; i++) dst[tid + 256 * i] = src[tid + 256 * i];
    }
    __syncthreads();

    int rbase = m0 + w * 32;
    if (rbase >= 2 * NN) return;   // wave-granular tail (after the only barrier)

    size_t rb0 = (size_t)(rbase + fm) * DD + kq * 8;
    size_t rb1 = rb0 + (size_t)16 * DD;
    const unsigned short* pA0 = AH + rb0;
    const unsigned short* pA1 = AH + rb1;
    const unsigned short* pXH0 = XH + rb0;
    const unsigned short* pXH1 = XH + rb1;
    const unsigned short* pXL0 = XL + rb0;
    const unsigned short* pXL1 = XL + rb1;
    const unsigned short* pWl = sW + lane * 8;

    f32x4 acc[2][2];
#pragma unroll
    for (int i = 0; i < 2; i++)
#pragma unroll
        for (int j = 0; j < 2; j++) acc[i][j] = (f32x4){0.f, 0.f, 0.f, 0.f};

#pragma unroll
    for (int c = 0; c < 8; c++) {
        bf16x8 a0h, a1h, a0l, a1l;
        if (c < 4) {                        // agg @ Wl : hi-only A
            a0h = *(const bf16x8*)(pA0 + c * 32);
            a1h = *(const bf16x8*)(pA1 + c * 32);
        } else {                            // x @ Wr : hi+lo A
            a0h = *(const bf16x8*)(pXH0 + (c - 4) * 32);
            a1h = *(const bf16x8*)(pXH1 + (c - 4) * 32);
            a0l = *(const bf16x8*)(pXL0 + (c - 4) * 32);
            a1l = *(const bf16x8*)(pXL1 + (c - 4) * 32);
        }
        bf16x8 w0h = *(const bf16x8*)(pWl + c * 1024);
        bf16x8 w0l = *(const bf16x8*)(pWl + c * 1024 + 512);
        bf16x8 w1h = *(const bf16x8*)(pWl + (8 + c) * 1024);
        bf16x8 w1l = *(const bf16x8*)(pWl + (8 + c) * 1024 + 512);
        acc[0][0] = __builtin_amdgcn_mfma_f32_16x16x32_bf16(a0h, w0h, acc[0][0], 0, 0, 0);
        acc[0][0] = __builtin_amdgcn_mfma_f32_16x16x32_bf16(a0h, w0l, acc[0][0], 0, 0, 0);
        acc[0][1] = __builtin_amdgcn_mfma_f32_16x16x32_bf16(a0h, w1h, acc[0][1], 0, 0, 0);
        acc[0][1] = __builtin_amdgcn_mfma_f32_16x16x32_bf16(a0h, w1l, acc[0][1], 0, 0, 0);
        acc[1][0] = __builtin_amdgcn_mfma_f32_16x16x32_bf16(a1h, w0h, acc[1][0], 0, 0, 0);
        acc[1][0] = __builtin_amdgcn_mfma_f32_16x16x32_bf16(a1h, w0l, acc[1][0], 0, 0, 0);
        acc[1][1] = __builtin_amdgcn_mfma_f32_16x16x32_bf16(a1h, w1h, acc[1][1], 0, 0, 0);
        acc[1][1] = __builtin_amdgcn_mfma_f32_16x16x32_bf16(a1h, w1l, acc[1][1], 0, 0, 0);
        if (c >= 4) {
            acc[0][0] = __builtin_amdgcn_mfma_f32_16x16x32_bf16(a0l, w0h, acc[0][0], 0, 0, 0);
            acc[0][1] = __builtin_amdgcn_mfma_f32_16x16x32_bf16(a0l, w1h, acc[0][1], 0, 0, 0);
            acc[1][0] = __builtin_amdgcn_mfma_f32_16x16x32_bf16(a1l, w0h, acc[1][0], 0, 0, 0);
            acc[1][1] = __builtin_amdgcn_mfma_f32_16x16x32_bf16(a1l, w1h, acc[1][1], 0, 0, 0);
        }
    }

    float scv[2], shv[2];
#pragma unroll
    for (int nt = 0; nt < 2; nt++) {
        int jj = grp * 32 + nt * 16 + fm;
        float s = g[jj] * rsqrtf(vr[jj] + EPSV);
        scv[nt] = s;
        shv[nt] = (bl[jj] - mn[jj]) * s + be[jj];
    }
#pragma unroll
    for (int mt = 0; mt < 2; mt++) {
#pragma unroll
        for (int r = 0; r < 4; r++) {
            int grow = rbase + mt * 16 + kq * 4 + r;
#pragma unroll
            for (int nt = 0; nt < 2; nt++) {
                int gcol = grp * 32 + nt * 16 + fm;
                float o = fmaxf(acc[mt][nt][r] * scv[nt] + shv[nt], 0.f);
                if (f32out) {
                    Of[(size_t)grow * DD + gcol] = o;
                } else {
                    unsigned short h = f2bf(o);
                    OH[(size_t)grow * DD + gcol] = h;
                    OL[(size_t)grow * DD + gcol] = f2bf(o - bf2f(h));
                }
            }
        }
    }
}

// ---------------- global add pool (atomic-free: batch sorted; both sides) ----------------
__launch_bounds__(128)
__global__ void k_pool2(const float* __restrict__ cf, const int* __restrict__ bt1,
                        const int* __restrict__ bt2, float* __restrict__ ppool) {
    int side = (blockIdx.x >= NB) ? 1 : 0;
    int b = blockIdx.x - side * NB;
    const int* batch = side ? bt2 : bt1;
    const float* h = cf + (size_t)side * NN * DD;
    __shared__ int sr[2];
    if (threadIdx.x < 2) {
        int target = b + (int)threadIdx.x;
        int lo = 0, hi = NN;
        while (lo < hi) {
            int mid = (lo + hi) >> 1;
            if (batch[mid] < target) lo = mid + 1; else hi = mid;
        }
        sr[threadIdx.x] = lo;
    }
    __syncthreads();
    int beg = sr[0], end = sr[1];
    int t = threadIdx.x;
    float acc = 0.f;
    for (int r = beg; r < end; r++) acc += h[(size_t)r * DD + t];
    ppool[((size_t)side * NB + b) * DD + t] = acc;
}

// ---------------- z build: concat(p1,p2,kge[rel]) -> hi/lo planes [NB][384] ----------------
__global__ void k_zb(const float* __restrict__ ppool, const int* __restrict__ rel,
                     const float* __restrict__ kge,
                     unsigned short* __restrict__ zh, unsigned short* __restrict__ zl) {
    int t = blockIdx.x * 256 + threadIdx.x;
    if (t >= NB * 384) return;
    int b = t / 384;
    int j = t - b * 384;
    float v;
    if (j < 128) v = ppool[(size_t)b * DD + j];
    else if (j < 256) v = ppool[(size_t)NB * DD + (size_t)b * DD + (j - 128)];
    else v = kge[(size_t)rel[b] * 128 + (j - 256)];
    unsigned short h = f2bf(v);
    zh[t] = h;
    zl[t] = f2bf(v - bf2f(h));
}

// ---------------- MLP head: split-bf16 MFMA GEMM + fused relu·W2 reduction ----------------
// M=NB (graphs), K=384, N=128. BM=32, BN=128; 256 threads = 4 waves, each wave 32 cols.
__launch_bounds__(256)
__global__ void k_mlp2(const unsigned short* __restrict__ zh, const unsigned short* __restrict__ zl,
                       const unsigned* __restrict__ w1p,
                       const float* __restrict__ b1, const float* __restrict__ W2,
                       const float* __restrict__ b2, float* __restrict__ out) {
    __shared__ __align__(16) unsigned short sZ[2][32 * 40];
    __shared__ __align__(16) unsigned short sW[2][128 * 40];
    __shared__ float hpart[32][4];
    int tid = threadIdx.x;
    int m0 = blockIdx.x * 32;
    int lane = tid & 63, w = tid >> 6;
    int fm = lane & 15, q = lane >> 4;
    int wn = w * 32;

    f32x4 acc[2][2];
#pragma unroll
    for (int i = 0; i < 2; i++)
#pragma unroll
        for (int j = 0; j < 2; j++) acc[i][j] = (f32x4){0.f, 0.f, 0.f, 0.f};

    for (int c = 0; c < 12; c++) {
        int k0 = c * 32;
        __syncthreads();
        {   // Z: 32 rows x 8 segs = 256 slots
            int row = tid >> 3, seg = tid & 7;
            size_t off = (size_t)(m0 + row) * 384 + k0 + seg * 4;
            *(ushort4*)&sZ[0][row * 40 + seg * 4] = *(const ushort4*)(zh + off);
            *(ushort4*)&sZ[1][row * 40 + seg * 4] = *(const ushort4*)(zl + off);
        }
#pragma unroll
        for (int i = 0; i < 4; i++) {   // W1: 128 rows x 8 segs = 1024 slots
            int u = tid + 256 * i;
            int row = u >> 3, seg = u & 7;
            uint4 val = *(const uint4*)(w1p + (size_t)row * 384 + k0 + seg * 4);
            ushort4 hi, lo;
            hi.x = val.x >> 16; hi.y = val.y >> 16; hi.z = val.z >> 16; hi.w = val.w >> 16;
            lo.x = val.x & 0xFFFF; lo.y = val.y & 0xFFFF; lo.z = val.z & 0xFFFF; lo.w = val.w & 0xFFFF;
            *(ushort4*)&sW[0][row * 40 + seg * 4] = hi;
            *(ushort4*)&sW[1][row * 40 + seg * 4] = lo;
        }
        __syncthreads();
        bf16x8 zfh[2], zfl[2];
#pragma unroll
        for (int mt = 0; mt < 2; mt++) {
            int r = mt * 16 + fm;
            zfh[mt] = *(const bf16x8*)&sZ[0][r * 40 + q * 8];
            zfl[mt] = *(const bf16x8*)&sZ[1][r * 40 + q * 8];
        }
#pragma unroll
        for (int nt = 0; nt < 2; nt++) {
            int nr = wn + nt * 16 + fm;
            bf16x8 wh = *(const bf16x8*)&sW[0][nr * 40 + q * 8];
            bf16x8 wl = *(const bf16x8*)&sW[1][nr * 40 + q * 8];
#pragma unroll
            for (int mt = 0; mt < 2; mt++) {
                acc[mt][nt] = __builtin_amdgcn_mfma_f32_16x16x32_bf16(zfh[mt], wh, acc[mt][nt], 0, 0, 0);
                acc[mt][nt] = __builtin_amdgcn_mfma_f32_16x16x32_bf16(zfh[mt], wl, acc[mt][nt], 0, 0, 0);
                acc[mt][nt] = __builtin_amdgcn_mfma_f32_16x16x32_bf16(zfl[mt], wh, acc[mt][nt], 0, 0, 0);
            }
        }
    }

    float b1v[2], w2v[2];
#pragma unroll
    for (int nt = 0; nt < 2; nt++) {
        int col = wn + nt * 16 + fm;
        b1v[nt] = b1[col];
        w2v[nt] = W2[col];
    }
#pragma unroll
    for (int mt = 0; mt < 2; mt++) {
#pragma unroll
        for (int r = 0; r < 4; r++) {
            float val = 0.f;
#pragma unroll
            for (int nt = 0; nt < 2; nt++)
                val += fmaxf(acc[mt][nt][r] + b1v[nt], 0.f) * w2v[nt];
#pragma unroll
            for (int m = 1; m < 16; m <<= 1) val += __shfl_xor(val, m, 64);
            if (fm == 0) hpart[mt * 16 + q * 4 + r][w] = val;
        }
    }
    __syncthreads();
    if (tid < 32)
        out[m0 + tid] = hpart[tid][0] + hpart[tid][1] + hpart[tid][2] + hpart[tid][3] + b2[0];
}

extern "C" void kernel_launch(void* const* d_in, const int* in_sizes, int n_in,
                              void* d_out, int out_size, void* d_ws, size_t ws_size,
                              hipStream_t stream) {
    const float* x1  = (const float*)d_in[0];
    const float* x2  = (const float*)d_in[1];
    const int*   ei1 = (const int*)d_in[2];
    const int*   ei2 = (const int*)d_in[3];
    const int*   bt1 = (const int*)d_in[4];
    const int*   bt2 = (const int*)d_in[5];
    const int*   rel = (const int*)d_in[6];
    const float* Wl  = (const float*)d_in[7];
    const float* bl  = (const float*)d_in[8];
    const float* Wr  = (const float*)d_in[9];
    const float* g   = (const float*)d_in[10];
    const float* be  = (const float*)d_in[11];
    const float* mn  = (const float*)d_in[12];
    const float* vr  = (const float*)d_in[13];
    const float* kge = (const float*)d_in[14];
    const float* W1  = (const float*)d_in[15];
    const float* b1v = (const float*)d_in[16];
    const float* W2  = (const float*)d_in[17];
    const float* b2v = (const float*)d_in[18];

    char* ws = (char*)d_ws;
    size_t off = 0;
    auto alloc = [&](size_t bytes) {
        void* p = ws + off;
        off += (bytes + 255) & ~(size_t)255;
        return p;
    };
    const size_t PL = (size_t)2 * NN * DD;      // elements per plane
    unsigned short* xbufH = (unsigned short*)alloc(PL * 2);
    unsigned short* xbufL = (unsigned short*)alloc(PL * 2);
    unsigned short* obufH = (unsigned short*)alloc(PL * 2);   // cf aliases obufH+obufL
    unsigned short* obufL = (unsigned short*)alloc(PL * 2);
    unsigned short* aggH  = (unsigned short*)alloc(PL * 2);
    unsigned short* wf = (unsigned short*)alloc((size_t)3 * 65536 * 2);   // fragment-linear SAGE W
    unsigned* wtp  = (unsigned*)alloc((size_t)128 * 384 * 4);             // MLP W1 packed
    float* ppool   = (float*)alloc((size_t)2 * NB * DD * 4);
    unsigned short* zh = (unsigned short*)alloc((size_t)NB * 384 * 2);
    unsigned short* zl = (unsigned short*)alloc((size_t)NB * 384 * 2);
    int*   bcnt    = (int*)alloc((size_t)2 * NCHUNK * NBKT * 4);
    int*   btot    = (int*)alloc((size_t)2 * NBKT * 4);
    int*   bbase   = (int*)alloc((size_t)2 * NBKT * 4);
    int*   part    = (int*)alloc((size_t)2 * NE * 4);
    int*   ptrC    = (int*)alloc((size_t)(2 * NN + 1) * 4);
    float* invdC   = (float*)alloc((size_t)2 * NN * 4);
    int*   csrC    = (int*)alloc((size_t)2 * NE * 4);
    if (off > ws_size) return;

    float* cf = (float*)obufH;   // 2NN*DD fp32 spans obufH+obufL (contiguous)

    const int nbCvt   = 12500;                       // 2*NN*32 / 256
    const int nbNode4 = (2 * NN + 3) / 4;            // 25000
    const int nbGemm3 = ((2 * NN + 127) / 128) * 4;  // 782 row-blocks x 4 col-groups = 3128
    const int nbW     = (128 * 384 + 255) / 256;
    const int nbWf    = (3 * 128 * 256 + 255) / 256;

    k_wcvt<<<nbW, 256, 0, stream>>>(W1, wtp);
    k_wfrag<<<nbWf, 256, 0, stream>>>(Wl, Wr, wf);

    // atomic-free combined CSR build (LDS atomics only)
    k_hist<<<2 * NCHUNK, 256, 0, stream>>>(ei1 + NE, ei2 + NE, bcnt);
    k_s1<<<2 * NBKT, 256, 0, stream>>>(bcnt, btot);
    k_s2<<<2, 256, 0, stream>>>(btot, bbase, ptrC);
    k_part<<<2 * NCHUNK, 256, 0, stream>>>(ei1, ei1 + NE, ei2, ei2 + NE, bcnt, bbase, part);
    k_csr<<<2 * NBKT, 256, 0, stream>>>(part, bbase, ptrC, invdC, csrC);

    k_cvt<<<nbCvt, 256, 0, stream>>>(x1, x2, xbufH, xbufL);

    // layer 0
    k_gather<<<nbNode4, 256, 0, stream>>>(xbufH, ptrC, csrC, invdC, aggH);
    k_gemm3<<<nbGemm3, 256, 0, stream>>>(aggH, xbufH, xbufL, wf, bl, g, be, mn, vr,
                                         obufH, obufL, (float*)nullptr, 0);
    // layer 1
    k_gather<<<nbNode4, 256, 0, stream>>>(obufH, ptrC, csrC, invdC, aggH);
    k_gemm3<<<nbGemm3, 256, 0, stream>>>(aggH, obufH, obufL, wf + 65536, bl + 128, g + 128,
                                         be + 128, mn + 128, vr + 128,
                                         xbufH, xbufL, (float*)nullptr, 0);
    // layer 2 -> fp32 (aliases obuf)
    k_gather<<<nbNode4, 256, 0, stream>>>(xbufH, ptrC, csrC, invdC, aggH);
    k_gemm3<<<nbGemm3, 256, 0, stream>>>(aggH, xbufH, xbufL, wf + 131072, bl + 256, g + 256,
                                         be + 256, mn + 256, vr + 256,
                                         (unsigned short*)nullptr, (unsigned short*)nullptr, cf, 1);

    k_pool2<<<2 * NB, 128, 0, stream>>>(cf, bt1, bt2, ppool);
    k_zb<<<(NB * 384 + 255) / 256, 256, 0, stream>>>(ppool, rel, kge, zh, zl);
    k_mlp2<<<NB / 32, 256, 0, stream>>>(zh, zl, wtp, b1v, W2, b2v, (float*)d_out);
}

// Round 4
// 488.201 us; speedup vs baseline: 1.0406x; 1.0406x over previous
//
#include <hip/hip_runtime.h>

#define NN 50000
#define NE 600000
#define NB 4096
#define DD 128
#define EPSV 1e-5f
#define NBKT 196     // ceil(50000/256) buckets of 256 node ids (per side)
#define NCHUNK 256   // edge chunks per side
#define CHSZ ((NE + NCHUNK - 1) / NCHUNK)   // 2344

typedef __bf16 bf16x8 __attribute__((ext_vector_type(8)));
typedef float f32x4 __attribute__((ext_vector_type(4)));

__device__ inline unsigned short f2bf(float f) {
    unsigned u = __float_as_uint(f);
    u = (u + 0x7FFFu + ((u >> 16) & 1u)) >> 16;
    return (unsigned short)u;
}
__device__ inline float bf2f(unsigned short h) {
    return __uint_as_float(((unsigned)h) << 16);
}

// ---------------- input conversion: fp32 -> hi/lo bf16 planes (both sides) ----------------
__global__ void k_cvt(const float* __restrict__ x1, const float* __restrict__ x2,
                      unsigned short* __restrict__ xh, unsigned short* __restrict__ xl) {
    int i = blockIdx.x * 256 + threadIdx.x;          // over 2*NN*32 float4 groups
    if (i >= 2 * NN * 32) return;
    const float* x = (i < NN * 32) ? x1 : x2;
    int j = (i < NN * 32) ? i : i - NN * 32;
    float4 v = ((const float4*)x)[j];
    ushort4 h, l;
    h.x = f2bf(v.x); l.x = f2bf(v.x - bf2f(h.x));
    h.y = f2bf(v.y); l.y = f2bf(v.y - bf2f(h.y));
    h.z = f2bf(v.z); l.z = f2bf(v.z - bf2f(h.z));
    h.w = f2bf(v.w); l.w = f2bf(v.w - bf2f(h.w));
    ((ushort4*)xh)[i] = h;
    ((ushort4*)xl)[i] = l;
}

// weights packed hi|lo uint: Wt[layer][n][k], k<128 -> Wl[k][n], k>=128 -> Wr[k-128][n];
// then W1t[n][k] (k in [0,384)) at offset 98304
__global__ void k_wcvt(const float* __restrict__ Wl, const float* __restrict__ Wr,
                       const float* __restrict__ W1, unsigned* __restrict__ wtp) {
    int t = blockIdx.x * 256 + threadIdx.x;
    if (t >= 3 * 128 * 256 + 128 * 384) return;
    float w;
    if (t < 3 * 128 * 256) {
        int k = t & 255;
        int n = (t >> 8) & 127;
        int l = t >> 15;
        w = (k < 128) ? Wl[l * 16384 + k * 128 + n] : Wr[l * 16384 + (k - 128) * 128 + n];
    } else {
        int u = t - 3 * 128 * 256;
        int n = u / 384;
        int k = u - n * 384;
        w = W1[k * 128 + n];
    }
    unsigned short h = f2bf(w);
    unsigned short l = f2bf(w - bf2f(h));
    wtp[t] = ((unsigned)h << 16) | (unsigned)l;
}

// ---------------- CSR build: atomic-free two-level counting sort (LDS atomics only) ----------------
__global__ void k_hist(const int* __restrict__ d0, const int* __restrict__ d1,
                       int* __restrict__ bcnt) {
    int side = (blockIdx.x >= NCHUNK) ? 1 : 0;
    int c = blockIdx.x - side * NCHUNK;
    const int* dst = side ? d1 : d0;
    int tid = threadIdx.x;
    __shared__ int h[NBKT];
    for (int i = tid; i < NBKT; i += 256) h[i] = 0;
    __syncthreads();
    int e0 = c * CHSZ, e1 = min(e0 + CHSZ, NE);
    for (int e = e0 + tid; e < e1; e += 256) atomicAdd(&h[dst[e] >> 8], 1);
    __syncthreads();
    int* bc = bcnt + ((size_t)side * NCHUNK + c) * NBKT;
    for (int i = tid; i < NBKT; i += 256) bc[i] = h[i];
}

__global__ void k_s1(int* __restrict__ bcnt, int* __restrict__ btot) {
    int side = (blockIdx.x >= NBKT) ? 1 : 0;
    int b = blockIdx.x - side * NBKT;
    int tid = threadIdx.x;            // tid == chunk
    int idx = ((size_t)side * NCHUNK + tid) * NBKT + b;
    int v = bcnt[idx];
    int lane = tid & 63, wv = tid >> 6;
    int x = v;
#pragma unroll
    for (int off = 1; off < 64; off <<= 1) {
        int y = __shfl_up(x, off, 64);
        if (lane >= off) x += y;
    }
    __shared__ int ws4[4];
    if (lane == 63) ws4[wv] = x;
    __syncthreads();
    int add = 0;
#pragma unroll
    for (int w = 0; w < 4; w++)
        if (w < wv) add += ws4[w];
    int incl = x + add;
    bcnt[idx] = incl - v;
    if (tid == 255) btot[side * NBKT + b] = incl;
}

__global__ void k_s2(const int* __restrict__ btot, int* __restrict__ bbase,
                     int* __restrict__ ptrC) {
    int side = blockIdx.x;
    int tid = threadIdx.x;
    int v = (tid < NBKT) ? btot[side * NBKT + tid] : 0;
    int lane = tid & 63, wv = tid >> 6;
    int x = v;
#pragma unroll
    for (int off = 1; off < 64; off <<= 1) {
        int y = __shfl_up(x, off, 64);
        if (lane >= off) x += y;
    }
    __shared__ int ws4[4];
    if (lane == 63) ws4[wv] = x;
    __syncthreads();
    int add = 0;
#pragma unroll
    for (int w = 0; w < 4; w++)
        if (w < wv) add += ws4[w];
    int incl = x + add;
    if (tid < NBKT) bbase[side * NBKT + tid] = incl - v;
    if (tid == 0 && side == 1) ptrC[2 * NN] = 2 * NE;
}

// partition: part[side*NE + pos] = (src_global << 8) | (dst & 255)
__global__ void k_part(const int* __restrict__ s0, const int* __restrict__ d0,
                       const int* __restrict__ s1, const int* __restrict__ d1,
                       const int* __restrict__ bcnt, const int* __restrict__ bbase,
                       int* __restrict__ part) {
    int side = (blockIdx.x >= NCHUNK) ? 1 : 0;
    int c = blockIdx.x - side * NCHUNK;
    const int* src = side ? s1 : s0;
    const int* dst = side ? d1 : d0;
    int tid = threadIdx.x;
    __shared__ int off[NBKT];
    const int* bc = bcnt + ((size_t)side * NCHUNK + c) * NBKT;
    for (int i = tid; i < NBKT; i += 256) off[i] = bbase[side * NBKT + i] + bc[i];
    __syncthreads();
    int e0 = c * CHSZ, e1 = min(e0 + CHSZ, NE);
    int* P = part + (size_t)side * NE;
    int soff = side * NN;
    for (int e = e0 + tid; e < e1; e += 256) {
        int d = dst[e];
        int pos = atomicAdd(&off[d >> 8], 1);
        P[pos] = ((src[e] + soff) << 8) | (d & 255);
    }
}

// per bucket: count, scan -> ptrC/invd (combined), place src into combined CSR
__global__ void k_csr(const int* __restrict__ part, const int* __restrict__ bbase,
                      int* __restrict__ ptrC, float* __restrict__ invdC,
                      int* __restrict__ csrC) {
    int side = (blockIdx.x >= NBKT) ? 1 : 0;
    int b = blockIdx.x - side * NBKT;
    int tid = threadIdx.x;
    const int* P = part + (size_t)side * NE;
    int base = bbase[side * NBKT + b];
    int endp = (b == NBKT - 1) ? NE : bbase[side * NBKT + b + 1];
    __shared__ int cnt[256];
    cnt[tid] = 0;
    __syncthreads();
    for (int e = base + tid; e < endp; e += 256) atomicAdd(&cnt[P[e] & 255], 1);
    __syncthreads();
    int v = cnt[tid];
    int lane = tid & 63, wv = tid >> 6;
    int x = v;
#pragma unroll
    for (int off = 1; off < 64; off <<= 1) {
        int y = __shfl_up(x, off, 64);
        if (lane >= off) x += y;
    }
    __shared__ int ws4[4];
    if (lane == 63) ws4[wv] = x;
    __syncthreads();
    int add = 0;
#pragma unroll
    for (int w = 0; w < 4; w++)
        if (w < wv) add += ws4[w];
    int excl = x + add - v;
    int node = (b << 8) + tid;
    if (node < NN) {
        ptrC[side * NN + node] = side * NE + base + excl;
        invdC[side * NN + node] = 1.0f / (float)(v > 1 ? v : 1);
    }
    __syncthreads();
    cnt[tid] = excl;
    __syncthreads();
    for (int e = base + tid; e < endp; e += 256) {
        int p = P[e];
        int pos = atomicAdd(&cnt[p & 255], 1);
        csrC[(size_t)side * NE + base + pos] = p >> 8;
    }
}

// ---------------- fused SAGE layer: gather(mean-agg) -> LDS -> MFMA GEMM + BN + relu -----------
// Block = 256 threads (4 waves), tile = 64 rows x 128 cols (FULL N -> A read/staged once).
// Phase 1: each wave gathers 16 rows' neighbor-mean (R1-gather inner loop) into sAgg (bf16 hi),
//          killing the aggH global roundtrip entirely.
// Phase 2: R1's proven chunked-LDS MFMA loop; chunks 0-3 (agg@Wl) read A from sAgg with NO
//          staging; chunks 4-7 (x@Wr) stage XH/XL into an LDS buffer that reuses sAgg's space.
// LDS = 37 KB -> 4 blocks/CU = 16 waves/CU.
__launch_bounds__(256, 4)
__global__ void k_fuse(const unsigned short* __restrict__ XH, const unsigned short* __restrict__ XL,
                       const int* __restrict__ ptr, const int* __restrict__ csr,
                       const float* __restrict__ invd,
                       const unsigned* __restrict__ Wtp,
                       const float* __restrict__ bl, const float* __restrict__ g,
                       const float* __restrict__ be, const float* __restrict__ mn,
                       const float* __restrict__ vr,
                       unsigned short* __restrict__ OH, unsigned short* __restrict__ OL,
                       float* __restrict__ Of, int f32out) {
    // sBuf union: phase1 + chunks 0-3: sAgg[64][136] (8704 shorts)
    //             chunks 4-7: sA hi [0,2560), sA lo [2560,5120)
    __shared__ __align__(16) unsigned short sBuf[8704];
    __shared__ __align__(16) unsigned short sW[2][128 * 40];
    int tid = threadIdx.x;
    int lane = tid & 63, w = tid >> 6;
    int fm = lane & 15, kq = lane >> 4;
    int m0 = blockIdx.x * 64;

    // ---------------- phase 1: gather 16 nodes per wave into sAgg ----------------
    for (int i = 0; i < 16; i++) {
        int n = m0 + w * 16 + i;
        int beg = 0, end = 0;
        float id = 0.f;
        if (n < 2 * NN) { beg = ptr[n]; end = ptr[n + 1]; id = invd[n]; }
        float a[8];
#pragma unroll
        for (int k = 0; k < 8; k++) a[k] = 0.f;
        for (int base = beg; base < end; base += 64) {
            int cnt = min(end - base, 64);
            int idxv = csr[base + min(lane, cnt - 1)];
            for (int e0 = 0; e0 < cnt; e0 += 8) {
                int eA = e0 + kq;
                int eB = e0 + 4 + kq;
                int iA = __shfl(idxv, eA, 64);
                int iB = __shfl(idxv, eB, 64);
                float wA = (eA < cnt) ? 1.f : 0.f;
                float wB = (eB < cnt) ? 1.f : 0.f;
                uint4 vA = *(const uint4*)(XH + (((unsigned)iA << 7) + (fm << 3)));
                uint4 vB = *(const uint4*)(XH + (((unsigned)iB << 7) + (fm << 3)));
                a[0] += wA * __uint_as_float(vA.x << 16);
                a[1] += wA * __uint_as_float(vA.x & 0xffff0000u);
                a[2] += wA * __uint_as_float(vA.y << 16);
                a[3] += wA * __uint_as_float(vA.y & 0xffff0000u);
                a[4] += wA * __uint_as_float(vA.z << 16);
                a[5] += wA * __uint_as_float(vA.z & 0xffff0000u);
                a[6] += wA * __uint_as_float(vA.w << 16);
                a[7] += wA * __uint_as_float(vA.w & 0xffff0000u);
                a[0] += wB * __uint_as_float(vB.x << 16);
                a[1] += wB * __uint_as_float(vB.x & 0xffff0000u);
                a[2] += wB * __uint_as_float(vB.y << 16);
                a[3] += wB * __uint_as_float(vB.y & 0xffff0000u);
                a[4] += wB * __uint_as_float(vB.z << 16);
                a[5] += wB * __uint_as_float(vB.z & 0xffff0000u);
                a[6] += wB * __uint_as_float(vB.w << 16);
                a[7] += wB * __uint_as_float(vB.w & 0xffff0000u);
            }
        }
#pragma unroll
        for (int k = 0; k < 8; k++) {
            a[k] += __shfl_xor(a[k], 16, 64);
            a[k] += __shfl_xor(a[k], 32, 64);
        }
        if (kq == 0) {
            unsigned short h0 = f2bf(a[0] * id), h1 = f2bf(a[1] * id);
            unsigned short h2 = f2bf(a[2] * id), h3 = f2bf(a[3] * id);
            unsigned short h4 = f2bf(a[4] * id), h5 = f2bf(a[5] * id);
            unsigned short h6 = f2bf(a[6] * id), h7 = f2bf(a[7] * id);
            uint4 o;
            o.x = (unsigned)h0 | ((unsigned)h1 << 16);
            o.y = (unsigned)h2 | ((unsigned)h3 << 16);
            o.z = (unsigned)h4 | ((unsigned)h5 << 16);
            o.w = (unsigned)h6 | ((unsigned)h7 << 16);
            *(uint4*)&sBuf[(w * 16 + i) * 136 + fm * 8] = o;
        }
    }
    __syncthreads();

    // ---------------- phase 2: MFMA GEMM over 8 k-chunks ----------------
    int wr = (w & 1) * 32;       // wave row offset (0/32)
    int wn = (w >> 1) * 64;      // wave col offset (0/64)

    f32x4 acc[2][4];
#pragma unroll
    for (int i = 0; i < 2; i++)
#pragma unroll
        for (int j = 0; j < 4; j++) acc[i][j] = (f32x4){0.f, 0.f, 0.f, 0.f};

    for (int c = 0; c < 8; c++) {
        int isA = (c < 4);
        if (c > 0) __syncthreads();          // prev-chunk readers done before restage
        if (!isA) {
            // stage X chunk (hi+lo): 64 rows x 32 k
#pragma unroll
            for (int i = 0; i < 2; i++) {
                int u = tid + 256 * i;
                int row = u >> 3, seg = u & 7;
                int grow = m0 + row;
                size_t goff = (size_t)grow * DD + (c - 4) * 32 + seg * 4;
                ushort4 hv = make_ushort4(0, 0, 0, 0), lv = make_ushort4(0, 0, 0, 0);
                if (grow < 2 * NN) {
                    hv = *(const ushort4*)(XH + goff);
                    lv = *(const ushort4*)(XL + goff);
                }
                *(ushort4*)&sBuf[row * 40 + seg * 4] = hv;
                *(ushort4*)&sBuf[2560 + row * 40 + seg * 4] = lv;
            }
        }
        // stage W chunk: 128 n-rows x 32 k (hi+lo)
#pragma unroll
        for (int i = 0; i < 4; i++) {
            int u = tid + 256 * i;
            int row = u >> 3, seg = u & 7;
            uint4 val = *(const uint4*)(Wtp + (size_t)row * 256 + c * 32 + seg * 4);
            ushort4 hi, lo;
            hi.x = val.x >> 16; hi.y = val.y >> 16; hi.z = val.z >> 16; hi.w = val.w >> 16;
            lo.x = val.x & 0xFFFF; lo.y = val.y & 0xFFFF; lo.z = val.z & 0xFFFF; lo.w = val.w & 0xFFFF;
            *(ushort4*)&sW[0][row * 40 + seg * 4] = hi;
            *(ushort4*)&sW[1][row * 40 + seg * 4] = lo;
        }
        __syncthreads();

        bf16x8 a0h, a1h, a0l, a1l;
        if (isA) {
            a0h = *(const bf16x8*)&sBuf[(wr + fm) * 136 + c * 32 + kq * 8];
            a1h = *(const bf16x8*)&sBuf[(wr + 16 + fm) * 136 + c * 32 + kq * 8];
        } else {
            a0h = *(const bf16x8*)&sBuf[(wr + fm) * 40 + kq * 8];
            a1h = *(const bf16x8*)&sBuf[(wr + 16 + fm) * 40 + kq * 8];
            a0l = *(const bf16x8*)&sBuf[2560 + (wr + fm) * 40 + kq * 8];
            a1l = *(const bf16x8*)&sBuf[2560 + (wr + 16 + fm) * 40 + kq * 8];
        }
#pragma unroll
        for (int nt = 0; nt < 4; nt++) {
            int nr = wn + nt * 16 + fm;
            bf16x8 wh = *(const bf16x8*)&sW[0][nr * 40 + kq * 8];
            bf16x8 wl = *(const bf16x8*)&sW[1][nr * 40 + kq * 8];
            acc[0][nt] = __builtin_amdgcn_mfma_f32_16x16x32_bf16(a0h, wh, acc[0][nt], 0, 0, 0);
            acc[0][nt] = __builtin_amdgcn_mfma_f32_16x16x32_bf16(a0h, wl, acc[0][nt], 0, 0, 0);
            acc[1][nt] = __builtin_amdgcn_mfma_f32_16x16x32_bf16(a1h, wh, acc[1][nt], 0, 0, 0);
            acc[1][nt] = __builtin_amdgcn_mfma_f32_16x16x32_bf16(a1h, wl, acc[1][nt], 0, 0, 0);
            if (!isA) {
                acc[0][nt] = __builtin_amdgcn_mfma_f32_16x16x32_bf16(a0l, wh, acc[0][nt], 0, 0, 0);
                acc[1][nt] = __builtin_amdgcn_mfma_f32_16x16x32_bf16(a1l, wh, acc[1][nt], 0, 0, 0);
            }
        }
    }

    float scv[4], shv[4];
#pragma unroll
    for (int nt = 0; nt < 4; nt++) {
        int jj = wn + nt * 16 + fm;
        float s = g[jj] * rsqrtf(vr[jj] + EPSV);
        scv[nt] = s;
        shv[nt] = (bl[jj] - mn[jj]) * s + be[jj];
    }
#pragma unroll
    for (int mt = 0; mt < 2; mt++) {
#pragma unroll
        for (int r = 0; r < 4; r++) {
            int grow = m0 + wr + mt * 16 + kq * 4 + r;
            if (grow < 2 * NN) {
#pragma unroll
                for (int nt = 0; nt < 4; nt++) {
                    int gcol = wn + nt * 16 + fm;
                    float o = fmaxf(acc[mt][nt][r] * scv[nt] + shv[nt], 0.f);
                    if (f32out) {
                        Of[(size_t)grow * DD + gcol] = o;
                    } else {
                        unsigned short h = f2bf(o);
                        OH[(size_t)grow * DD + gcol] = h;
                        OL[(size_t)grow * DD + gcol] = f2bf(o - bf2f(h));
                    }
                }
            }
        }
    }
}

// ---------------- global add pool (atomic-free: batch sorted; both sides) ----------------
__launch_bounds__(128)
__global__ void k_pool2(const float* __restrict__ cf, const int* __restrict__ bt1,
                        const int* __restrict__ bt2, float* __restrict__ ppool) {
    int side = (blockIdx.x >= NB) ? 1 : 0;
    int b = blockIdx.x - side * NB;
    const int* batch = side ? bt2 : bt1;
    const float* h = cf + (size_t)side * NN * DD;
    __shared__ int sr[2];
    if (threadIdx.x < 2) {
        int target = b + (int)threadIdx.x;
        int lo = 0, hi = NN;
        while (lo < hi) {
            int mid = (lo + hi) >> 1;
            if (batch[mid] < target) lo = mid + 1; else hi = mid;
        }
        sr[threadIdx.x] = lo;
    }
    __syncthreads();
    int beg = sr[0], end = sr[1];
    int t = threadIdx.x;
    float acc = 0.f;
    for (int r = beg; r < end; r++) acc += h[(size_t)r * DD + t];
    ppool[((size_t)side * NB + b) * DD + t] = acc;
}

// ---------------- z build: concat(p1,p2,kge[rel]) -> hi/lo planes [NB][384] ----------------
__global__ void k_zb(const float* __restrict__ ppool, const int* __restrict__ rel,
                     const float* __restrict__ kge,
                     unsigned short* __restrict__ zh, unsigned short* __restrict__ zl) {
    int t = blockIdx.x * 256 + threadIdx.x;
    if (t >= NB * 384) return;
    int b = t / 384;
    int j = t - b * 384;
    float v;
    if (j < 128) v = ppool[(size_t)b * DD + j];
    else if (j < 256) v = ppool[(size_t)NB * DD + (size_t)b * DD + (j - 128)];
    else v = kge[(size_t)rel[b] * 128 + (j - 256)];
    unsigned short h = f2bf(v);
    zh[t] = h;
    zl[t] = f2bf(v - bf2f(h));
}

// ---------------- MLP head: split-bf16 MFMA GEMM + fused relu·W2 reduction ----------------
// M=NB (graphs), K=384, N=128. BM=32, BN=128; 256 threads = 4 waves, each wave 32 cols.
__launch_bounds__(256)
__global__ void k_mlp2(const unsigned short* __restrict__ zh, const unsigned short* __restrict__ zl,
                       const unsigned* __restrict__ w1p,
                       const float* __restrict__ b1, const float* __restrict__ W2,
                       const float* __restrict__ b2, float* __restrict__ out) {
    __shared__ __align__(16) unsigned short sZ[2][32 * 40];
    __shared__ __align__(16) unsigned short sW[2][128 * 40];
    __shared__ float hpart[32][4];
    int tid = threadIdx.x;
    int m0 = blockIdx.x * 32;
    int lane = tid & 63, w = tid >> 6;
    int fm = lane & 15, q = lane >> 4;
    int wn = w * 32;

    f32x4 acc[2][2];
#pragma unroll
    for (int i = 0; i < 2; i++)
#pragma unroll
        for (int j = 0; j < 2; j++) acc[i][j] = (f32x4){0.f, 0.f, 0.f, 0.f};

    for (int c = 0; c < 12; c++) {
        int k0 = c * 32;
        __syncthreads();
        {   // Z: 32 rows x 8 segs = 256 slots
            int row = tid >> 3, seg = tid & 7;
            size_t off = (size_t)(m0 + row) * 384 + k0 + seg * 4;
            *(ushort4*)&sZ[0][row * 40 + seg * 4] = *(const ushort4*)(zh + off);
            *(ushort4*)&sZ[1][row * 40 + seg * 4] = *(const ushort4*)(zl + off);
        }
#pragma unroll
        for (int i = 0; i < 4; i++) {   // W1: 128 rows x 8 segs = 1024 slots
            int u = tid + 256 * i;
            int row = u >> 3, seg = u & 7;
            uint4 val = *(const uint4*)(w1p + (size_t)row * 384 + k0 + seg * 4);
            ushort4 hi, lo;
            hi.x = val.x >> 16; hi.y = val.y >> 16; hi.z = val.z >> 16; hi.w = val.w >> 16;
            lo.x = val.x & 0xFFFF; lo.y = val.y & 0xFFFF; lo.z = val.z & 0xFFFF; lo.w = val.w & 0xFFFF;
            *(ushort4*)&sW[0][row * 40 + seg * 4] = hi;
            *(ushort4*)&sW[1][row * 40 + seg * 4] = lo;
        }
        __syncthreads();
        bf16x8 zfh[2], zfl[2];
#pragma unroll
        for (int mt = 0; mt < 2; mt++) {
            int r = mt * 16 + fm;
            zfh[mt] = *(const bf16x8*)&sZ[0][r * 40 + q * 8];
            zfl[mt] = *(const bf16x8*)&sZ[1][r * 40 + q * 8];
        }
#pragma unroll
        for (int nt = 0; nt < 2; nt++) {
            int nr = wn + nt * 16 + fm;
            bf16x8 wh = *(const bf16x8*)&sW[0][nr * 40 + q * 8];
            bf16x8 wl = *(const bf16x8*)&sW[1][nr * 40 + q * 8];
#pragma unroll
            for (int mt = 0; mt < 2; mt++) {
                acc[mt][nt] = __builtin_amdgcn_mfma_f32_16x16x32_bf16(zfh[mt], wh, acc[mt][nt], 0, 0, 0);
                acc[mt][nt] = __builtin_amdgcn_mfma_f32_16x16x32_bf16(zfh[mt], wl, acc[mt][nt], 0, 0, 0);
                acc[mt][nt] = __builtin_amdgcn_mfma_f32_16x16x32_bf16(zfl[mt], wh, acc[mt][nt], 0, 0, 0);
            }
        }
    }

    float b1v[2], w2v[2];
#pragma unroll
    for (int nt = 0; nt < 2; nt++) {
        int col = wn + nt * 16 + fm;
        b1v[nt] = b1[col];
        w2v[nt] = W2[col];
    }
#pragma unroll
    for (int mt = 0; mt < 2; mt++) {
#pragma unroll
        for (int r = 0; r < 4; r++) {
            float val = 0.f;
#pragma unroll
            for (int nt = 0; nt < 2; nt++)
                val += fmaxf(acc[mt][nt][r] + b1v[nt], 0.f) * w2v[nt];
#pragma unroll
            for (int m = 1; m < 16; m <<= 1) val += __shfl_xor(val, m, 64);
            if (fm == 0) hpart[mt * 16 + q * 4 + r][w] = val;
        }
    }
    __syncthreads();
    if (tid < 32)
        out[m0 + tid] = hpart[tid][0] + hpart[tid][1] + hpart[tid][2] + hpart[tid][3] + b2[0];
}

extern "C" void kernel_launch(void* const* d_in, const int* in_sizes, int n_in,
                              void* d_out, int out_size, void* d_ws, size_t ws_size,
                              hipStream_t stream) {
    const float* x1  = (const float*)d_in[0];
    const float* x2  = (const float*)d_in[1];
    const int*   ei1 = (const int*)d_in[2];
    const int*   ei2 = (const int*)d_in[3];
    const int*   bt1 = (const int*)d_in[4];
    const int*   bt2 = (const int*)d_in[5];
    const int*   rel = (const int*)d_in[6];
    const float* Wl  = (const float*)d_in[7];
    const float* bl  = (const float*)d_in[8];
    const float* Wr  = (const float*)d_in[9];
    const float* g   = (const float*)d_in[10];
    const float* be  = (const float*)d_in[11];
    const float* mn  = (const float*)d_in[12];
    const float* vr  = (const float*)d_in[13];
    const float* kge = (const float*)d_in[14];
    const float* W1  = (const float*)d_in[15];
    const float* b1v = (const float*)d_in[16];
    const float* W2  = (const float*)d_in[17];
    const float* b2v = (const float*)d_in[18];

    char* ws = (char*)d_ws;
    size_t off = 0;
    auto alloc = [&](size_t bytes) {
        void* p = ws + off;
        off += (bytes + 255) & ~(size_t)255;
        return p;
    };
    const size_t PL = (size_t)2 * NN * DD;      // elements per plane
    unsigned short* xbufH = (unsigned short*)alloc(PL * 2);
    unsigned short* xbufL = (unsigned short*)alloc(PL * 2);
    unsigned short* obufH = (unsigned short*)alloc(PL * 2);   // cf aliases obufH+obufL
    unsigned short* obufL = (unsigned short*)alloc(PL * 2);
    unsigned* wtp  = (unsigned*)alloc((size_t)(3 * 128 * 256 + 128 * 384) * 4);
    float* ppool   = (float*)alloc((size_t)2 * NB * DD * 4);
    unsigned short* zh = (unsigned short*)alloc((size_t)NB * 384 * 2);
    unsigned short* zl = (unsigned short*)alloc((size_t)NB * 384 * 2);
    int*   bcnt    = (int*)alloc((size_t)2 * NCHUNK * NBKT * 4);
    int*   btot    = (int*)alloc((size_t)2 * NBKT * 4);
    int*   bbase   = (int*)alloc((size_t)2 * NBKT * 4);
    int*   part    = (int*)alloc((size_t)2 * NE * 4);
    int*   ptrC    = (int*)alloc((size_t)(2 * NN + 1) * 4);
    float* invdC   = (float*)alloc((size_t)2 * NN * 4);
    int*   csrC    = (int*)alloc((size_t)2 * NE * 4);
    if (off > ws_size) return;

    float* cf = (float*)obufH;   // 2NN*DD fp32 spans obufH+obufL (contiguous)

    const int nbCvt  = 12500;                        // 2*NN*32 / 256
    const int nbFuse = (2 * NN + 63) / 64;           // 1563
    const int nbW    = (3 * 128 * 256 + 128 * 384 + 255) / 256;

    k_wcvt<<<nbW, 256, 0, stream>>>(Wl, Wr, W1, wtp);

    // atomic-free combined CSR build (LDS atomics only)
    k_hist<<<2 * NCHUNK, 256, 0, stream>>>(ei1 + NE, ei2 + NE, bcnt);
    k_s1<<<2 * NBKT, 256, 0, stream>>>(bcnt, btot);
    k_s2<<<2, 256, 0, stream>>>(btot, bbase, ptrC);
    k_part<<<2 * NCHUNK, 256, 0, stream>>>(ei1, ei1 + NE, ei2, ei2 + NE, bcnt, bbase, part);
    k_csr<<<2 * NBKT, 256, 0, stream>>>(part, bbase, ptrC, invdC, csrC);

    k_cvt<<<nbCvt, 256, 0, stream>>>(x1, x2, xbufH, xbufL);

    // layer 0: gather+gemm fused
    k_fuse<<<nbFuse, 256, 0, stream>>>(xbufH, xbufL, ptrC, csrC, invdC, wtp,
                                       bl, g, be, mn, vr,
                                       obufH, obufL, (float*)nullptr, 0);
    // layer 1
    k_fuse<<<nbFuse, 256, 0, stream>>>(obufH, obufL, ptrC, csrC, invdC, wtp + 32768,
                                       bl + 128, g + 128, be + 128, mn + 128, vr + 128,
                                       xbufH, xbufL, (float*)nullptr, 0);
    // layer 2 -> fp32 (aliases obuf)
    k_fuse<<<nbFuse, 256, 0, stream>>>(xbufH, xbufL, ptrC, csrC, invdC, wtp + 65536,
                                       bl + 256, g + 256, be + 256, mn + 256, vr + 256,
                                       (unsigned short*)nullptr, (unsigned short*)nullptr, cf, 1);

    k_pool2<<<2 * NB, 128, 0, stream>>>(cf, bt1, bt2, ppool);
    k_zb<<<(NB * 384 + 255) / 256, 256, 0, stream>>>(ppool, rel, kge, zh, zl);
    k_mlp2<<<NB / 32, 256, 0, stream>>>(zh, zl, wtp + 98304, b1v, W2, b2v, (float*)d_out);
}

// Round 5
// 445.120 us; speedup vs baseline: 1.1413x; 1.0968x over previous
//
#include <hip/hip_runtime.h>

#define NN 50000
#define NE 600000
#define NB 4096
#define DD 128
#define EPSV 1e-5f
#define NBKT 196     // ceil(50000/256) buckets of 256 node ids (per side)
#define NCHUNK 256   // edge chunks per side
#define CHSZ ((NE + NCHUNK - 1) / NCHUNK)   // 2344

typedef __bf16 bf16x8 __attribute__((ext_vector_type(8)));
typedef float f32x4 __attribute__((ext_vector_type(4)));
typedef float f32x2 __attribute__((ext_vector_type(2)));

__device__ inline unsigned short f2bf(float f) {
    unsigned u = __float_as_uint(f);
    u = (u + 0x7FFFu + ((u >> 16) & 1u)) >> 16;
    return (unsigned short)u;
}
__device__ inline float bf2f(unsigned short h) {
    return __uint_as_float(((unsigned)h) << 16);
}

// ---------------- input conversion: fp32 -> hi/lo bf16 planes (both sides) ----------------
__global__ void k_cvt(const float* __restrict__ x1, const float* __restrict__ x2,
                      unsigned short* __restrict__ xh, unsigned short* __restrict__ xl) {
    int i = blockIdx.x * 256 + threadIdx.x;          // over 2*NN*32 float4 groups
    if (i >= 2 * NN * 32) return;
    const float* x = (i < NN * 32) ? x1 : x2;
    int j = (i < NN * 32) ? i : i - NN * 32;
    float4 v = ((const float4*)x)[j];
    ushort4 h, l;
    h.x = f2bf(v.x); l.x = f2bf(v.x - bf2f(h.x));
    h.y = f2bf(v.y); l.y = f2bf(v.y - bf2f(h.y));
    h.z = f2bf(v.z); l.z = f2bf(v.z - bf2f(h.z));
    h.w = f2bf(v.w); l.w = f2bf(v.w - bf2f(h.w));
    ((ushort4*)xh)[i] = h;
    ((ushort4*)xl)[i] = l;
}

// SAGE weights -> chunk-linear hi/lo bf16 planes for direct 16B LDS staging:
//   per layer l, per k-chunk c (32 k): hi[n*32 + kk] at l*65536 + c*8192, lo at +4096.
// k<128 -> Wl[l][k][n] (agg operand), k>=128 -> Wr[l][k-128][n] (self operand).
// Plus MLP W1 packed hi|lo uint: w1p[n*384 + k].
__global__ void k_wcvt(const float* __restrict__ Wl, const float* __restrict__ Wr,
                       const float* __restrict__ W1,
                       unsigned short* __restrict__ wfp, unsigned* __restrict__ w1p) {
    int t = blockIdx.x * 256 + threadIdx.x;
    if (t < 3 * 128 * 256) {
        int k = t & 255;
        int n = (t >> 8) & 127;
        int l = t >> 15;
        float w = (k < 128) ? Wl[l * 16384 + k * 128 + n] : Wr[l * 16384 + (k - 128) * 128 + n];
        unsigned short h = f2bf(w);
        unsigned short lo = f2bf(w - bf2f(h));
        int c = k >> 5, kk = k & 31;
        size_t base = (size_t)l * 65536 + (size_t)c * 8192 + n * 32 + kk;
        wfp[base] = h;
        wfp[base + 4096] = lo;
    } else if (t < 3 * 128 * 256 + 128 * 384) {
        int u = t - 3 * 128 * 256;
        int n = u / 384;
        int k = u - n * 384;
        float w = W1[k * 128 + n];
        unsigned short h = f2bf(w);
        unsigned short l = f2bf(w - bf2f(h));
        w1p[u] = ((unsigned)h << 16) | (unsigned)l;
    }
}

// ---------------- CSR build: atomic-free two-level counting sort (LDS atomics only) ----------------
__global__ void k_hist(const int* __restrict__ d0, const int* __restrict__ d1,
                       int* __restrict__ bcnt) {
    int side = (blockIdx.x >= NCHUNK) ? 1 : 0;
    int c = blockIdx.x - side * NCHUNK;
    const int* dst = side ? d1 : d0;
    int tid = threadIdx.x;
    __shared__ int h[NBKT];
    for (int i = tid; i < NBKT; i += 256) h[i] = 0;
    __syncthreads();
    int e0 = c * CHSZ, e1 = min(e0 + CHSZ, NE);
    for (int e = e0 + tid; e < e1; e += 256) atomicAdd(&h[dst[e] >> 8], 1);
    __syncthreads();
    int* bc = bcnt + ((size_t)side * NCHUNK + c) * NBKT;
    for (int i = tid; i < NBKT; i += 256) bc[i] = h[i];
}

__global__ void k_s1(int* __restrict__ bcnt, int* __restrict__ btot) {
    int side = (blockIdx.x >= NBKT) ? 1 : 0;
    int b = blockIdx.x - side * NBKT;
    int tid = threadIdx.x;            // tid == chunk
    int idx = ((size_t)side * NCHUNK + tid) * NBKT + b;
    int v = bcnt[idx];
    int lane = tid & 63, wv = tid >> 6;
    int x = v;
#pragma unroll
    for (int off = 1; off < 64; off <<= 1) {
        int y = __shfl_up(x, off, 64);
        if (lane >= off) x += y;
    }
    __shared__ int ws4[4];
    if (lane == 63) ws4[wv] = x;
    __syncthreads();
    int add = 0;
#pragma unroll
    for (int w = 0; w < 4; w++)
        if (w < wv) add += ws4[w];
    int incl = x + add;
    bcnt[idx] = incl - v;
    if (tid == 255) btot[side * NBKT + b] = incl;
}

__global__ void k_s2(const int* __restrict__ btot, int* __restrict__ bbase,
                     int* __restrict__ ptrC) {
    int side = blockIdx.x;
    int tid = threadIdx.x;
    int v = (tid < NBKT) ? btot[side * NBKT + tid] : 0;
    int lane = tid & 63, wv = tid >> 6;
    int x = v;
#pragma unroll
    for (int off = 1; off < 64; off <<= 1) {
        int y = __shfl_up(x, off, 64);
        if (lane >= off) x += y;
    }
    __shared__ int ws4[4];
    if (lane == 63) ws4[wv] = x;
    __syncthreads();
    int add = 0;
#pragma unroll
    for (int w = 0; w < 4; w++)
        if (w < wv) add += ws4[w];
    int incl = x + add;
    if (tid < NBKT) bbase[side * NBKT + tid] = incl - v;
    if (tid == 0 && side == 1) ptrC[2 * NN] = 2 * NE;
}

// partition: part[side*NE + pos] = (src_global << 8) | (dst & 255)
__global__ void k_part(const int* __restrict__ s0, const int* __restrict__ d0,
                       const int* __restrict__ s1, const int* __restrict__ d1,
                       const int* __restrict__ bcnt, const int* __restrict__ bbase,
                       int* __restrict__ part) {
    int side = (blockIdx.x >= NCHUNK) ? 1 : 0;
    int c = blockIdx.x - side * NCHUNK;
    const int* src = side ? s1 : s0;
    const int* dst = side ? d1 : d0;
    int tid = threadIdx.x;
    __shared__ int off[NBKT];
    const int* bc = bcnt + ((size_t)side * NCHUNK + c) * NBKT;
    for (int i = tid; i < NBKT; i += 256) off[i] = bbase[side * NBKT + i] + bc[i];
    __syncthreads();
    int e0 = c * CHSZ, e1 = min(e0 + CHSZ, NE);
    int* P = part + (size_t)side * NE;
    int soff = side * NN;
    for (int e = e0 + tid; e < e1; e += 256) {
        int d = dst[e];
        int pos = atomicAdd(&off[d >> 8], 1);
        P[pos] = ((src[e] + soff) << 8) | (d & 255);
    }
}

// per bucket: count, scan -> ptrC/invd (combined), place src into combined CSR
__global__ void k_csr(const int* __restrict__ part, const int* __restrict__ bbase,
                      int* __restrict__ ptrC, float* __restrict__ invdC,
                      int* __restrict__ csrC) {
    int side = (blockIdx.x >= NBKT) ? 1 : 0;
    int b = blockIdx.x - side * NBKT;
    int tid = threadIdx.x;
    const int* P = part + (size_t)side * NE;
    int base = bbase[side * NBKT + b];
    int endp = (b == NBKT - 1) ? NE : bbase[side * NBKT + b + 1];
    __shared__ int cnt[256];
    cnt[tid] = 0;
    __syncthreads();
    for (int e = base + tid; e < endp; e += 256) atomicAdd(&cnt[P[e] & 255], 1);
    __syncthreads();
    int v = cnt[tid];
    int lane = tid & 63, wv = tid >> 6;
    int x = v;
#pragma unroll
    for (int off = 1; off < 64; off <<= 1) {
        int y = __shfl_up(x, off, 64);
        if (lane >= off) x += y;
    }
    __shared__ int ws4[4];
    if (lane == 63) ws4[wv] = x;
    __syncthreads();
    int add = 0;
#pragma unroll
    for (int w = 0; w < 4; w++)
        if (w < wv) add += ws4[w];
    int excl = x + add - v;
    int node = (b << 8) + tid;
    if (node < NN) {
        ptrC[side * NN + node] = side * NE + base + excl;
        invdC[side * NN + node] = 1.0f / (float)(v > 1 ? v : 1);
    }
    __syncthreads();
    cnt[tid] = excl;
    __syncthreads();
    for (int e = base + tid; e < endp; e += 256) {
        int p = P[e];
        int pos = atomicAdd(&cnt[p & 255], 1);
        csrC[(size_t)side * NE + base + pos] = p >> 8;
    }
}

// ---------------- neighbor mean-aggregation (hi plane in, hi plane out; both sides) ----------------
// One wave per node; coalesced csr index load + __shfl distribution; 16 lanes/row x uint4.
// Accumulation in packed f32x2 -> v_pk_fma_f32 halves FMA instruction count.
__global__ void k_gather(const unsigned short* __restrict__ xh, const int* __restrict__ ptr,
                         const int* __restrict__ csr, const float* __restrict__ invd,
                         unsigned short* __restrict__ aggH) {
    int wid = threadIdx.x >> 6;
    int lane = threadIdx.x & 63;
    int q = lane >> 4;        // edge slot within group of 4
    int c = lane & 15;        // column chunk: elems [c*8, c*8+8)
    int n = blockIdx.x * 4 + wid;
    if (n >= 2 * NN) return;
    int beg = ptr[n], end = ptr[n + 1];
    float id = invd[n];
    f32x2 a2[4];
#pragma unroll
    for (int k = 0; k < 4; k++) a2[k] = (f32x2){0.f, 0.f};

    for (int base = beg; base < end; base += 64) {
        int cnt = min(end - base, 64);
        int idxv = csr[base + min(lane, cnt - 1)];
        for (int e0 = 0; e0 < cnt; e0 += 8) {
            int eA = e0 + q;
            int eB = e0 + 4 + q;
            int iA = __shfl(idxv, eA, 64);
            int iB = __shfl(idxv, eB, 64);
            f32x2 wA2 = (eA < cnt) ? (f32x2){1.f, 1.f} : (f32x2){0.f, 0.f};
            f32x2 wB2 = (eB < cnt) ? (f32x2){1.f, 1.f} : (f32x2){0.f, 0.f};
            uint4 vA = *(const uint4*)(xh + (((unsigned)iA << 7) + (c << 3)));
            uint4 vB = *(const uint4*)(xh + (((unsigned)iB << 7) + (c << 3)));
            a2[0] += wA2 * (f32x2){__uint_as_float(vA.x << 16), __uint_as_float(vA.x & 0xffff0000u)};
            a2[1] += wA2 * (f32x2){__uint_as_float(vA.y << 16), __uint_as_float(vA.y & 0xffff0000u)};
            a2[2] += wA2 * (f32x2){__uint_as_float(vA.z << 16), __uint_as_float(vA.z & 0xffff0000u)};
            a2[3] += wA2 * (f32x2){__uint_as_float(vA.w << 16), __uint_as_float(vA.w & 0xffff0000u)};
            a2[0] += wB2 * (f32x2){__uint_as_float(vB.x << 16), __uint_as_float(vB.x & 0xffff0000u)};
            a2[1] += wB2 * (f32x2){__uint_as_float(vB.y << 16), __uint_as_float(vB.y & 0xffff0000u)};
            a2[2] += wB2 * (f32x2){__uint_as_float(vB.z << 16), __uint_as_float(vB.z & 0xffff0000u)};
            a2[3] += wB2 * (f32x2){__uint_as_float(vB.w << 16), __uint_as_float(vB.w & 0xffff0000u)};
        }
    }
    float a[8];
    a[0] = a2[0][0]; a[1] = a2[0][1];
    a[2] = a2[1][0]; a[3] = a2[1][1];
    a[4] = a2[2][0]; a[5] = a2[2][1];
    a[6] = a2[3][0]; a[7] = a2[3][1];
#pragma unroll
    for (int k = 0; k < 8; k++) {
        a[k] += __shfl_xor(a[k], 16, 64);
        a[k] += __shfl_xor(a[k], 32, 64);
    }
    if (q == 0) {
        unsigned short h0 = f2bf(a[0] * id), h1 = f2bf(a[1] * id);
        unsigned short h2 = f2bf(a[2] * id), h3 = f2bf(a[3] * id);
        unsigned short h4 = f2bf(a[4] * id), h5 = f2bf(a[5] * id);
        unsigned short h6 = f2bf(a[6] * id), h7 = f2bf(a[7] * id);
        uint4 o;
        o.x = (unsigned)h0 | ((unsigned)h1 << 16);
        o.y = (unsigned)h2 | ((unsigned)h3 << 16);
        o.z = (unsigned)h4 | ((unsigned)h5 << 16);
        o.w = (unsigned)h6 | ((unsigned)h7 << 16);
        *(uint4*)(aggH + (size_t)n * DD + c * 8) = o;
    }
}

// ---------------- fused SAGE layer GEMM: 128x128 tile, split-bf16 MFMA ----------------
// Block = 4 waves; tile = 128 rows x 128 cols; wave = 64x64 (4x4 fragments, 64 acc VGPR).
// Per 32-k chunk: stage A (16B slots, hi or hi+lo) + W (chunk-linear planes, pure 16B copy),
// 2 barriers, then 32-48 MFMA/wave -- 4x the MFMA per barrier of the 64x64 version.
// LDS 40 KB. A operand (agg) = hi only (2 MFMAs); X operand = hi+lo (3 MFMAs).
__launch_bounds__(256)
__global__ void k_gemmL(const unsigned short* __restrict__ AH,
                        const unsigned short* __restrict__ XH, const unsigned short* __restrict__ XL,
                        const unsigned short* __restrict__ wfp,
                        const float* __restrict__ bl, const float* __restrict__ g,
                        const float* __restrict__ be, const float* __restrict__ mn,
                        const float* __restrict__ vr,
                        unsigned short* __restrict__ OH, unsigned short* __restrict__ OL,
                        float* __restrict__ Of, int f32out) {
    __shared__ __align__(16) unsigned short sA[2][128 * 40];
    __shared__ __align__(16) unsigned short sW[2][128 * 40];
    int tid = threadIdx.x;
    int lane = tid & 63, w = tid >> 6;
    int fm = lane & 15, kq = lane >> 4;
    int m0 = blockIdx.x * 128;
    int wr = (w & 1) * 64;
    int wn = (w >> 1) * 64;

    f32x4 acc[4][4];
#pragma unroll
    for (int i = 0; i < 4; i++)
#pragma unroll
        for (int j = 0; j < 4; j++) acc[i][j] = (f32x4){0.f, 0.f, 0.f, 0.f};

    for (int c = 0; c < 8; c++) {
        int isA = (c < 4);
        if (c > 0) __syncthreads();
        // stage A: 128 rows x 32 k = 512 x 16B slots
#pragma unroll
        for (int i = 0; i < 2; i++) {
            int s = tid + 256 * i;
            int row = s >> 2, seg = s & 3;
            int grow = m0 + row;
            size_t goff = (size_t)grow * DD + (c & 3) * 32 + seg * 8;
            if (isA) {
                uint4 hv = make_uint4(0, 0, 0, 0);
                if (grow < 2 * NN) hv = *(const uint4*)(AH + goff);
                *(uint4*)&sA[0][row * 40 + seg * 8] = hv;
            } else {
                uint4 hv = make_uint4(0, 0, 0, 0), lv = make_uint4(0, 0, 0, 0);
                if (grow < 2 * NN) {
                    hv = *(const uint4*)(XH + goff);
                    lv = *(const uint4*)(XL + goff);
                }
                *(uint4*)&sA[0][row * 40 + seg * 8] = hv;
                *(uint4*)&sA[1][row * 40 + seg * 8] = lv;
            }
        }
        // stage W: chunk-linear planes, pure 16B copies
        const unsigned short* wb = wfp + (size_t)c * 8192;
#pragma unroll
        for (int i = 0; i < 2; i++) {
            int s = tid + 256 * i;
            int row = s >> 2, seg = s & 3;
            *(uint4*)&sW[0][row * 40 + seg * 8] = *(const uint4*)(wb + s * 8);
            *(uint4*)&sW[1][row * 40 + seg * 8] = *(const uint4*)(wb + 4096 + s * 8);
        }
        __syncthreads();

        bf16x8 ah[4], al[4];
#pragma unroll
        for (int mt = 0; mt < 4; mt++) {
            int r = wr + mt * 16 + fm;
            ah[mt] = *(const bf16x8*)&sA[0][r * 40 + kq * 8];
            if (!isA) al[mt] = *(const bf16x8*)&sA[1][r * 40 + kq * 8];
        }
#pragma unroll
        for (int nt = 0; nt < 4; nt++) {
            int nr = wn + nt * 16 + fm;
            bf16x8 wh = *(const bf16x8*)&sW[0][nr * 40 + kq * 8];
            bf16x8 wl = *(const bf16x8*)&sW[1][nr * 40 + kq * 8];
#pragma unroll
            for (int mt = 0; mt < 4; mt++) {
                acc[mt][nt] = __builtin_amdgcn_mfma_f32_16x16x32_bf16(ah[mt], wh, acc[mt][nt], 0, 0, 0);
                acc[mt][nt] = __builtin_amdgcn_mfma_f32_16x16x32_bf16(ah[mt], wl, acc[mt][nt], 0, 0, 0);
                if (!isA)
                    acc[mt][nt] = __builtin_amdgcn_mfma_f32_16x16x32_bf16(al[mt], wh, acc[mt][nt], 0, 0, 0);
            }
        }
    }

    float scv[4], shv[4];
#pragma unroll
    for (int nt = 0; nt < 4; nt++) {
        int jj = wn + nt * 16 + fm;
        float s = g[jj] * rsqrtf(vr[jj] + EPSV);
        scv[nt] = s;
        shv[nt] = (bl[jj] - mn[jj]) * s + be[jj];
    }
#pragma unroll
    for (int mt = 0; mt < 4; mt++) {
#pragma unroll
        for (int r = 0; r < 4; r++) {
            int grow = m0 + wr + mt * 16 + kq * 4 + r;
            if (grow < 2 * NN) {
#pragma unroll
                for (int nt = 0; nt < 4; nt++) {
                    int gcol = wn + nt * 16 + fm;
                    float o = fmaxf(acc[mt][nt][r] * scv[nt] + shv[nt], 0.f);
                    if (f32out) {
                        Of[(size_t)grow * DD + gcol] = o;
                    } else {
                        unsigned short h = f2bf(o);
                        OH[(size_t)grow * DD + gcol] = h;
                        OL[(size_t)grow * DD + gcol] = f2bf(o - bf2f(h));
                    }
                }
            }
        }
    }
}

// ---------------- global add pool fused with z build (atomic-free: batch sorted) ----------------
// Block (side,b): pool 128 cols of graph b, write z hi/lo directly; side-0 also writes kge cols.
__launch_bounds__(128)
__global__ void k_pool2z(const float* __restrict__ cf, const int* __restrict__ bt1,
                         const int* __restrict__ bt2, const int* __restrict__ rel,
                         const float* __restrict__ kge,
                         unsigned short* __restrict__ zh, unsigned short* __restrict__ zl) {
    int side = (blockIdx.x >= NB) ? 1 : 0;
    int b = blockIdx.x - side * NB;
    const int* batch = side ? bt2 : bt1;
    const float* h = cf + (size_t)side * NN * DD;
    __shared__ int sr[2];
    if (threadIdx.x < 2) {
        int target = b + (int)threadIdx.x;
        int lo = 0, hi = NN;
        while (lo < hi) {
            int mid = (lo + hi) >> 1;
            if (batch[mid] < target) lo = mid + 1; else hi = mid;
        }
        sr[threadIdx.x] = lo;
    }
    __syncthreads();
    int beg = sr[0], end = sr[1];
    int t = threadIdx.x;
    float acc = 0.f;
    for (int r = beg; r < end; r++) acc += h[(size_t)r * DD + t];
    size_t zo = (size_t)b * 384 + side * 128 + t;
    unsigned short hh = f2bf(acc);
    zh[zo] = hh;
    zl[zo] = f2bf(acc - bf2f(hh));
    if (side == 0) {
        float kv = kge[(size_t)rel[b] * 128 + t];
        size_t zk = (size_t)b * 384 + 256 + t;
        unsigned short kh = f2bf(kv);
        zh[zk] = kh;
        zl[zk] = f2bf(kv - bf2f(kh));
    }
}

// ---------------- MLP head: split-bf16 MFMA GEMM + fused relu·W2 reduction ----------------
// M=NB (graphs), K=384, N=128. BM=32, BN=128; 256 threads = 4 waves, each wave 32 cols.
__launch_bounds__(256)
__global__ void k_mlp2(const unsigned short* __restrict__ zh, const unsigned short* __restrict__ zl,
                       const unsigned* __restrict__ w1p,
                       const float* __restrict__ b1, const float* __restrict__ W2,
                       const float* __restrict__ b2, float* __restrict__ out) {
    __shared__ __align__(16) unsigned short sZ[2][32 * 40];
    __shared__ __align__(16) unsigned short sW[2][128 * 40];
    __shared__ float hpart[32][4];
    int tid = threadIdx.x;
    int m0 = blockIdx.x * 32;
    int lane = tid & 63, w = tid >> 6;
    int fm = lane & 15, q = lane >> 4;
    int wn = w * 32;

    f32x4 acc[2][2];
#pragma unroll
    for (int i = 0; i < 2; i++)
#pragma unroll
        for (int j = 0; j < 2; j++) acc[i][j] = (f32x4){0.f, 0.f, 0.f, 0.f};

    for (int c = 0; c < 12; c++) {
        int k0 = c * 32;
        __syncthreads();
        {   // Z: 32 rows x 8 segs = 256 slots
            int row = tid >> 3, seg = tid & 7;
            size_t off = (size_t)(m0 + row) * 384 + k0 + seg * 4;
            *(ushort4*)&sZ[0][row * 40 + seg * 4] = *(const ushort4*)(zh + off);
            *(ushort4*)&sZ[1][row * 40 + seg * 4] = *(const ushort4*)(zl + off);
        }
#pragma unroll
        for (int i = 0; i < 4; i++) {   // W1: 128 rows x 8 segs = 1024 slots
            int u = tid + 256 * i;
            int row = u >> 3, seg = u & 7;
            uint4 val = *(const uint4*)(w1p + (size_t)row * 384 + k0 + seg * 4);
            ushort4 hi, lo;
            hi.x = val.x >> 16; hi.y = val.y >> 16; hi.z = val.z >> 16; hi.w = val.w >> 16;
            lo.x = val.x & 0xFFFF; lo.y = val.y & 0xFFFF; lo.z = val.z & 0xFFFF; lo.w = val.w & 0xFFFF;
            *(ushort4*)&sW[0][row * 40 + seg * 4] = hi;
            *(ushort4*)&sW[1][row * 40 + seg * 4] = lo;
        }
        __syncthreads();
        bf16x8 zfh[2], zfl[2];
#pragma unroll
        for (int mt = 0; mt < 2; mt++) {
            int r = mt * 16 + fm;
            zfh[mt] = *(const bf16x8*)&sZ[0][r * 40 + q * 8];
            zfl[mt] = *(const bf16x8*)&sZ[1][r * 40 + q * 8];
        }
#pragma unroll
        for (int nt = 0; nt < 2; nt++) {
            int nr = wn + nt * 16 + fm;
            bf16x8 wh = *(const bf16x8*)&sW[0][nr * 40 + q * 8];
            bf16x8 wl = *(const bf16x8*)&sW[1][nr * 40 + q * 8];
#pragma unroll
            for (int mt = 0; mt < 2; mt++) {
                acc[mt][nt] = __builtin_amdgcn_mfma_f32_16x16x32_bf16(zfh[mt], wh, acc[mt][nt], 0, 0, 0);
                acc[mt][nt] = __builtin_amdgcn_mfma_f32_16x16x32_bf16(zfh[mt], wl, acc[mt][nt], 0, 0, 0);
                acc[mt][nt] = __builtin_amdgcn_mfma_f32_16x16x32_bf16(zfl[mt], wh, acc[mt][nt], 0, 0, 0);
            }
        }
    }

    float b1v[2], w2v[2];
#pragma unroll
    for (int nt = 0; nt < 2; nt++) {
        int col = wn + nt * 16 + fm;
        b1v[nt] = b1[col];
        w2v[nt] = W2[col];
    }
#pragma unroll
    for (int mt = 0; mt < 2; mt++) {
#pragma unroll
        for (int r = 0; r < 4; r++) {
            float val = 0.f;
#pragma unroll
            for (int nt = 0; nt < 2; nt++)
                val += fmaxf(acc[mt][nt][r] + b1v[nt], 0.f) * w2v[nt];
#pragma unroll
            for (int m = 1; m < 16; m <<= 1) val += __shfl_xor(val, m, 64);
            if (fm == 0) hpart[mt * 16 + q * 4 + r][w] = val;
        }
    }
    __syncthreads();
    if (tid < 32)
        out[m0 + tid] = hpart[tid][0] + hpart[tid][1] + hpart[tid][2] + hpart[tid][3] + b2[0];
}

extern "C" void kernel_launch(void* const* d_in, const int* in_sizes, int n_in,
                              void* d_out, int out_size, void* d_ws, size_t ws_size,
                              hipStream_t stream) {
    const float* x1  = (const float*)d_in[0];
    const float* x2  = (const float*)d_in[1];
    const int*   ei1 = (const int*)d_in[2];
    const int*   ei2 = (const int*)d_in[3];
    const int*   bt1 = (const int*)d_in[4];
    const int*   bt2 = (const int*)d_in[5];
    const int*   rel = (const int*)d_in[6];
    const float* Wl  = (const float*)d_in[7];
    const float* bl  = (const float*)d_in[8];
    const float* Wr  = (const float*)d_in[9];
    const float* g   = (const float*)d_in[10];
    const float* be  = (const float*)d_in[11];
    const float* mn  = (const float*)d_in[12];
    const float* vr  = (const float*)d_in[13];
    const float* kge = (const float*)d_in[14];
    const float* W1  = (const float*)d_in[15];
    const float* b1v = (const float*)d_in[16];
    const float* W2  = (const float*)d_in[17];
    const float* b2v = (const float*)d_in[18];

    char* ws = (char*)d_ws;
    size_t off = 0;
    auto alloc = [&](size_t bytes) {
        void* p = ws + off;
        off += (bytes + 255) & ~(size_t)255;
        return p;
    };
    const size_t PL = (size_t)2 * NN * DD;      // elements per plane
    unsigned short* xbufH = (unsigned short*)alloc(PL * 2);
    unsigned short* xbufL = (unsigned short*)alloc(PL * 2);
    unsigned short* obufH = (unsigned short*)alloc(PL * 2);   // cf aliases obufH+obufL
    unsigned short* obufL = (unsigned short*)alloc(PL * 2);
    unsigned short* aggH  = (unsigned short*)alloc(PL * 2);
    unsigned short* wfp   = (unsigned short*)alloc((size_t)3 * 65536 * 2);  // chunk-linear SAGE W
    unsigned* w1p  = (unsigned*)alloc((size_t)128 * 384 * 4);               // MLP W1 packed
    unsigned short* zh = (unsigned short*)alloc((size_t)NB * 384 * 2);
    unsigned short* zl = (unsigned short*)alloc((size_t)NB * 384 * 2);
    int*   bcnt    = (int*)alloc((size_t)2 * NCHUNK * NBKT * 4);
    int*   btot    = (int*)alloc((size_t)2 * NBKT * 4);
    int*   bbase   = (int*)alloc((size_t)2 * NBKT * 4);
    int*   part    = (int*)alloc((size_t)2 * NE * 4);
    int*   ptrC    = (int*)alloc((size_t)(2 * NN + 1) * 4);
    float* invdC   = (float*)alloc((size_t)2 * NN * 4);
    int*   csrC    = (int*)alloc((size_t)2 * NE * 4);
    if (off > ws_size) return;

    float* cf = (float*)obufH;   // 2NN*DD fp32 spans obufH+obufL (contiguous)

    const int nbCvt   = 12500;                       // 2*NN*32 / 256
    const int nbNode4 = (2 * NN + 3) / 4;            // 25000
    const int nbGemmL = (2 * NN + 127) / 128;        // 782
    const int nbW     = (3 * 128 * 256 + 128 * 384 + 255) / 256;

    k_wcvt<<<nbW, 256, 0, stream>>>(Wl, Wr, W1, wfp, w1p);

    // atomic-free combined CSR build (LDS atomics only)
    k_hist<<<2 * NCHUNK, 256, 0, stream>>>(ei1 + NE, ei2 + NE, bcnt);
    k_s1<<<2 * NBKT, 256, 0, stream>>>(bcnt, btot);
    k_s2<<<2, 256, 0, stream>>>(btot, bbase, ptrC);
    k_part<<<2 * NCHUNK, 256, 0, stream>>>(ei1, ei1 + NE, ei2, ei2 + NE, bcnt, bbase, part);
    k_csr<<<2 * NBKT, 256, 0, stream>>>(part, bbase, ptrC, invdC, csrC);

    k_cvt<<<nbCvt, 256, 0, stream>>>(x1, x2, xbufH, xbufL);

    // layer 0
    k_gather<<<nbNode4, 256, 0, stream>>>(xbufH, ptrC, csrC, invdC, aggH);
    k_gemmL<<<nbGemmL, 256, 0, stream>>>(aggH, xbufH, xbufL, wfp, bl, g, be, mn, vr,
                                         obufH, obufL, (float*)nullptr, 0);
    // layer 1
    k_gather<<<nbNode4, 256, 0, stream>>>(obufH, ptrC, csrC, invdC, aggH);
    k_gemmL<<<nbGemmL, 256, 0, stream>>>(aggH, obufH, obufL, wfp + 65536, bl + 128, g + 128,
                                         be + 128, mn + 128, vr + 128,
                                         xbufH, xbufL, (float*)nullptr, 0);
    // layer 2 -> fp32 (aliases obuf)
    k_gather<<<nbNode4, 256, 0, stream>>>(xbufH, ptrC, csrC, invdC, aggH);
    k_gemmL<<<nbGemmL, 256, 0, stream>>>(aggH, xbufH, xbufL, wfp + 131072, bl + 256, g + 256,
                                         be + 256, mn + 256, vr + 256,
                                         (unsigned short*)nullptr, (unsigned short*)nullptr, cf, 1);

    k_pool2z<<<2 * NB, 128, 0, stream>>>(cf, bt1, bt2, rel, kge, zh, zl);
    k_mlp2<<<NB / 32, 256, 0, stream>>>(zh, zl, w1p, b1v, W2, b2v, (float*)d_out);
}